// Round 13
// baseline (79.034 us; speedup 1.0000x reference)
//
#include <hip/hip_runtime.h>
#include <hip/hip_bf16.h>

typedef __attribute__((ext_vector_type(8))) short short8;
typedef __attribute__((ext_vector_type(4))) float f32x4;
typedef __attribute__((ext_vector_type(16))) float f32x16;

#define DEVI __device__ __forceinline__

DEVI unsigned short f2bf(float f) {
  union { float f; unsigned int u; } v; v.f = f;
  unsigned int r = v.u + 0x7fffu + ((v.u >> 16) & 1u);
  return (unsigned short)(r >> 16);
}

DEVI unsigned int cvt2(float lo, float hi) {  // v_cvt_pk_bf16_f32 (RNE)
  unsigned int r;
  asm("v_cvt_pk_bf16_f32 %0, %1, %2" : "=v"(r) : "v"(lo), "v"(hi));
  return r;
}

// direct global->LDS, 16B per lane. dest = wave-uniform base + lane*16 (linear).
#define GLDS16(gp, lp)                                                         \
  __builtin_amdgcn_global_load_lds(                                            \
      (const __attribute__((address_space(1))) unsigned int*)(uintptr_t)(gp),  \
      (__attribute__((address_space(3))) unsigned int*)(uintptr_t)(lp), 16, 0, 0)

// problem sizes
#define SB 4
#define SS 2048
#define SD 256
#define SH 8
#define SDH 32
#define SM 8192

#define QSCALE 0.0318793654f

// workspace layout (ushort element offsets)
#define Q_OFF   0                 // [BH][S][dh]   (Q pre-scaled by QSCALE)
#define K_OFF   (SM * SD)         // [BH][S][dh]
#define VT_OFF  (2 * SM * SD)     // [BH][dh][S]
#define AO_OFF  (3 * SM * SD)     // [M][D] attention output (read by final_k)
#define WF_OFF  (4 * SM * SD)     // [256][256] Wf bf16
#define AO2_OFF (WF_OFF + SD * SD) // scratch AO for instrumentation rep 1 (unread)

// ---------------- kernel 1: fused convert + QKV projection, 64x128 tile -----
// (byte-identical to the 54.9us R10 config)
__global__ __launch_bounds__(256) void qkv_k(
    const float* __restrict__ X, const float* __restrict__ Wq,
    const float* __restrict__ Wk, const float* __restrict__ Wv,
    const float* __restrict__ Wf, unsigned short* __restrict__ ws) {
  __shared__ __align__(16) unsigned short Atile[64][72];
  __shared__ __align__(16) unsigned short Btile[128][72];
  int tid = threadIdx.x, w = tid >> 6, lane = tid & 63, g = lane >> 4, r = lane & 15;
  int m0 = blockIdx.x * 64;
  int z = blockIdx.y >> 1, nbase = (blockIdx.y & 1) * 128;
  const float* Wz = (z == 0) ? Wq : (z == 1) ? Wk : Wv;
  if (z == 2) {  // Wf fp32 -> bf16, 256 floats per block (slice disjoint)
    int slice = blockIdx.x + (nbase ? 128 : 0);
    ws[WF_OFF + slice * 256 + tid] = f2bf(Wf[slice * 256 + tid]);
  }
  int wr = (w >> 1) * 32, wc = (w & 1) * 64;
  f32x4 acc[2][4] = {};
  int srow = tid >> 3, scol = (tid & 7) * 8;
  float4 a0[2], a1[2], b0[4], b1[4];
#pragma unroll
  for (int p = 0; p < 2; ++p) {
    const float* xa = X + (m0 + srow + p * 32) * SD + scol;
    a0[p] = *reinterpret_cast<const float4*>(xa);
    a1[p] = *reinterpret_cast<const float4*>(xa + 4);
  }
#pragma unroll
  for (int p = 0; p < 4; ++p) {
    const float* xb = Wz + (nbase + srow + p * 32) * SD + scol;
    b0[p] = *reinterpret_cast<const float4*>(xb);
    b1[p] = *reinterpret_cast<const float4*>(xb + 4);
  }
  for (int k0 = 0; k0 < SD; k0 += 64) {
    __syncthreads();
#pragma unroll
    for (int p = 0; p < 2; ++p) {
      uint4 ua = { cvt2(a0[p].x, a0[p].y), cvt2(a0[p].z, a0[p].w),
                   cvt2(a1[p].x, a1[p].y), cvt2(a1[p].z, a1[p].w) };
      *reinterpret_cast<uint4*>(&Atile[srow + p * 32][scol]) = ua;
    }
#pragma unroll
    for (int p = 0; p < 4; ++p) {
      uint4 ub = { cvt2(b0[p].x, b0[p].y), cvt2(b0[p].z, b0[p].w),
                   cvt2(b1[p].x, b1[p].y), cvt2(b1[p].z, b1[p].w) };
      *reinterpret_cast<uint4*>(&Btile[srow + p * 32][scol]) = ub;
    }
    __syncthreads();
    if (k0 + 64 < SD) {
#pragma unroll
      for (int p = 0; p < 2; ++p) {
        const float* xa = X + (m0 + srow + p * 32) * SD + k0 + 64 + scol;
        a0[p] = *reinterpret_cast<const float4*>(xa);
        a1[p] = *reinterpret_cast<const float4*>(xa + 4);
      }
#pragma unroll
      for (int p = 0; p < 4; ++p) {
        const float* xb = Wz + (nbase + srow + p * 32) * SD + k0 + 64 + scol;
        b0[p] = *reinterpret_cast<const float4*>(xb);
        b1[p] = *reinterpret_cast<const float4*>(xb + 4);
      }
    }
#pragma unroll
    for (int ks = 0; ks < 2; ++ks) {
      short8 af[2], bf[4];
#pragma unroll
      for (int i = 0; i < 2; ++i)
        af[i] = *reinterpret_cast<const short8*>(&Atile[wr + i * 16 + r][ks * 32 + g * 8]);
#pragma unroll
      for (int j = 0; j < 4; ++j)
        bf[j] = *reinterpret_cast<const short8*>(&Btile[wc + j * 16 + r][ks * 32 + g * 8]);
#pragma unroll
      for (int i = 0; i < 2; ++i)
#pragma unroll
        for (int j = 0; j < 4; ++j)
          acc[i][j] = __builtin_amdgcn_mfma_f32_16x16x32_bf16(af[i], bf[j], acc[i][j], 0, 0, 0);
    }
  }
  int b_ = m0 >> 11, sbase = m0 & 2047;
  float qs = (z == 0) ? QSCALE : 1.0f;
  unsigned short* Vt = &Btile[0][0];  // reused as [64 n][80 m-pad]
#pragma unroll
  for (int p = 0; p < 2; ++p) {       // n-half pass: local cols p*64 .. p*64+63
    __syncthreads();
    if ((w & 1) == p) {
      if (z < 2) {
#pragma unroll
        for (int i = 0; i < 2; ++i)
#pragma unroll
          for (int j = 0; j < 4; ++j)
#pragma unroll
            for (int jj = 0; jj < 4; ++jj)
              Atile[wr + i * 16 + g * 4 + jj][j * 16 + r] = f2bf(acc[i][j][jj] * qs);
      } else {
#pragma unroll
        for (int i = 0; i < 2; ++i)
#pragma unroll
          for (int j = 0; j < 4; ++j) {
            unsigned short o4[4];
#pragma unroll
            for (int jj = 0; jj < 4; ++jj) o4[jj] = f2bf(acc[i][j][jj]);
            *reinterpret_cast<uint2*>(&Vt[(j * 16 + r) * 80 + wr + i * 16 + g * 4]) =
                *reinterpret_cast<const uint2*>(o4);
          }
      }
    }
    __syncthreads();
    if (z < 2) {
      unsigned short* out = ws + (z == 0 ? Q_OFF : K_OFF);
      int h0 = (nbase + p * 64) >> 5;
#pragma unroll
      for (int it = 0; it < 2; ++it) {
        int c = it * 256 + tid;
        int m = c >> 3, cr = c & 7, hl = cr >> 2, ch = cr & 3;
        short8 val = *reinterpret_cast<const short8*>(&Atile[m][hl * 32 + ch * 8]);
        int h = h0 + hl;
        *reinterpret_cast<short8*>(
            out + (((b_ << 3) + h) * SS + sbase + m) * SDH + ch * 8) = val;
      }
    } else {
      unsigned short* out = ws + VT_OFF;
      int nb = nbase + p * 64;
#pragma unroll
      for (int it = 0; it < 2; ++it) {
        int c = it * 256 + tid;
        int nl = c >> 3, ch = c & 7;
        short8 val = *reinterpret_cast<const short8*>(&Vt[nl * 80 + ch * 8]);
        int col = nb + nl, h = col >> 5, d = col & 31;
        *reinterpret_cast<short8*>(
            out + ((((b_ << 3) + h) << 5) + d) * SS + sbase + ch * 8) = val;
      }
    }
  }
}

// ---------------- kernel 2: flash attention (R10 body; x2 with scratch AO) --
// rep 0 is EXACTLY the R10 flow writing the real AO (final_k reads only AO);
// rep 1 re-runs identical work but writes scratch AO2 (never read) -- so any
// rep-1 anomaly cannot affect correctness, while the dispatch doubles past the
// ~40us harness fills and surfaces in top-5 with counters.
__global__ __launch_bounds__(512, 4) void attn_k(const unsigned short* __restrict__ ws_c,
                                                 unsigned short* __restrict__ ws) {
  __shared__ __align__(16) unsigned char smem[65536];
  int tid = threadIdx.x, w = tid >> 6, lane = tid & 63;
  int wg = w >> 2, wl = w & 3, gtid = tid & 255;
  int n32 = lane & 31, hi = lane >> 5;
  int wgid = ((blockIdx.x & 7) << 6) + (blockIdx.x >> 3);
  int bh = wgid >> 4, qb = wgid & 15;
  int q0 = qb * 128 + wl * 32;
  const unsigned short* Qh = ws_c + Q_OFF + bh * (SS * SDH);
  const unsigned short* Kg = ws_c + K_OFF + (bh * SS + wg * 1024) * SDH;
  const unsigned short* Vg = ws_c + VT_OFF + bh * (SDH * SS) + wg * 1024;
  short8 qB0 = *reinterpret_cast<const short8*>(Qh + (q0 + n32) * SDH + 8 * hi);
  short8 qB1 = *reinterpret_cast<const short8*>(Qh + (q0 + n32) * SDH + 16 + 8 * hi);
  unsigned short* Kbuf0 = (unsigned short*)(smem + wg * 16384);
  unsigned short* Kbuf1 = (unsigned short*)(smem + wg * 16384 + 8192);
  unsigned short* Vbuf0 = (unsigned short*)(smem + 32768 + wg * 16384);
  unsigned short* Vbuf1 = (unsigned short*)(smem + 32768 + wg * 16384 + 8192);
  int wv = gtid >> 6;
  int kr = gtid >> 2;
  int kcg = (gtid & 3) ^ ((kr >> 1) & 3);
  const unsigned short* gK0 = Kg + kr * SDH + kcg * 8;
  const unsigned short* gK1 = gK0 + 64 * SDH;
  int vr = gtid >> 4;
  int vcg = (gtid & 15) ^ (vr & 7);
  const unsigned short* gV0 = Vg + vr * SS + vcg * 8;
  const unsigned short* gV1 = gV0 + 16 * SS;
  auto issue = [&](int buf, int tt) {
    char* kd = (char*)(buf ? Kbuf1 : Kbuf0) + wv * 1024;
    char* vd = (char*)(buf ? Vbuf1 : Vbuf0) + wv * 1024;
    GLDS16(gK0 + tt * 4096, kd);
    GLDS16(gK1 + tt * 4096, kd + 4096);
    GLDS16(gV0 + tt * 128, vd);
    GLDS16(gV1 + tt * 128, vd + 4096);
  };
  union { unsigned int u[4]; short8 sv; } ONES;
  ONES.u[0] = 0x3F803F80u; ONES.u[1] = 0x3F803F80u;
  ONES.u[2] = 0x3F803F80u; ONES.u[3] = 0x3F803F80u;
  int rb = (n32 >> 1) & 3;
  int koff0 = (hi ^ rb) * 8;
  int koff1 = ((2 + hi) ^ rb) * 8;
  int vb7 = n32 & 7;
  for (int rep = 0; rep < 2; ++rep) {
    if (rep) __syncthreads();  // rep0 combine LDS reads done before restaging
    issue(0, 0);
    f32x16 O = {}, Lf = {};
    for (int t = 0; t < 8; ++t) {
      const unsigned short* Kt = (t & 1) ? Kbuf1 : Kbuf0;
      const unsigned short* Vt = (t & 1) ? Vbuf1 : Vbuf0;
      if (t < 7) {
        issue((t + 1) & 1, t + 1);
        asm volatile("s_waitcnt vmcnt(4)" ::: "memory");
      } else {
        asm volatile("s_waitcnt vmcnt(0)" ::: "memory");
      }
      __builtin_amdgcn_s_barrier();
#pragma unroll
      for (int si = 0; si < 4; ++si) {
        int s = (si + wl) & 3;
        const unsigned short* krow = Kt + (s * 32 + n32) * 32;
        short8 ka = *reinterpret_cast<const short8*>(krow + koff0);
        short8 kb = *reinterpret_cast<const short8*>(krow + koff1);
        f32x16 aC = {};
        __builtin_amdgcn_s_setprio(1);
        aC = __builtin_amdgcn_mfma_f32_32x32x16_bf16(ka, qB0, aC, 0, 0, 0);
        aC = __builtin_amdgcn_mfma_f32_32x32x16_bf16(kb, qB1, aC, 0, 0, 0);
        __builtin_amdgcn_s_setprio(0);
#pragma unroll
        for (int i = 0; i < 16; ++i) aC[i] = __builtin_amdgcn_exp2f(aC[i]);
        unsigned int pk[8];
#pragma unroll
        for (int i = 0; i < 8; ++i) pk[i] = cvt2(aC[2 * i], aC[2 * i + 1]);
        asm("v_permlane32_swap_b32 %0, %1" : "+v"(pk[0]), "+v"(pk[2]));
        asm("v_permlane32_swap_b32 %0, %1" : "+v"(pk[1]), "+v"(pk[3]));
        asm("v_permlane32_swap_b32 %0, %1" : "+v"(pk[4]), "+v"(pk[6]));
        asm("v_permlane32_swap_b32 %0, %1" : "+v"(pk[5]), "+v"(pk[7]));
        union { unsigned int u[4]; short8 sv; } A1, A2;
        A1.u[0] = pk[0]; A1.u[1] = pk[1]; A1.u[2] = pk[2]; A1.u[3] = pk[3];
        A2.u[0] = pk[4]; A2.u[1] = pk[5]; A2.u[2] = pk[6]; A2.u[3] = pk[7];
        const unsigned short* vrow = Vt + n32 * 128;
        short8 vB0 = *reinterpret_cast<const short8*>(vrow + ((s * 4 + hi) ^ vb7) * 8);
        short8 vB1 = *reinterpret_cast<const short8*>(vrow + ((s * 4 + 2 + hi) ^ vb7) * 8);
        __builtin_amdgcn_s_setprio(1);
        O  = __builtin_amdgcn_mfma_f32_32x32x16_bf16(A1.sv, vB0, O, 0, 0, 0);
        O  = __builtin_amdgcn_mfma_f32_32x32x16_bf16(A2.sv, vB1, O, 0, 0, 0);
        Lf = __builtin_amdgcn_mfma_f32_32x32x16_bf16(A1.sv, ONES.sv, Lf, 0, 0, 0);
        Lf = __builtin_amdgcn_mfma_f32_32x32x16_bf16(A2.sv, ONES.sv, Lf, 0, 0, 0);
        __builtin_amdgcn_s_setprio(0);
      }
      __builtin_amdgcn_s_barrier();
    }
    __syncthreads();
    float* OCf = reinterpret_cast<float*>(smem);           // [16][257]
    float* LCf = OCf + 16 * 257;
    int p = wl * 64 + lane;
    if (wg == 1) {
#pragma unroll
      for (int i = 0; i < 16; ++i) { OCf[i * 257 + p] = O[i]; LCf[i * 257 + p] = Lf[i]; }
    }
    __syncthreads();
    if (wg == 0) {
      int b = bh >> 3, h = bh & 7;
      unsigned short* AO = ws + (rep ? AO2_OFF : AO_OFF);  // rep1 -> scratch
#pragma unroll
      for (int rr = 0; rr < 16; ++rr) {
        float Ot = O[rr] + OCf[rr * 257 + p];
        float Lt = Lf[rr] + LCf[rr * 257 + p];
        int q = (rr & 3) + 8 * (rr >> 2) + 4 * hi;
        AO[(b * SS + q0 + q) * SD + h * SDH + n32] = f2bf(Ot / Lt);
      }
    }
  }
}

// ---------------- kernel 3: out-proj + bias + residual + LayerNorm ----------
// (byte-identical to the 54.9us R10 config)
__global__ __launch_bounds__(256) void final_k(
    const unsigned short* __restrict__ ws_c, const float* __restrict__ X,
    const float* __restrict__ bfv, const float* __restrict__ gamma,
    const float* __restrict__ beta, float* __restrict__ out) {
  __shared__ __align__(16) unsigned short Al[16][72];
  __shared__ __align__(16) unsigned short Bl[256][72];
  __shared__ float Cl[16][257];
  const unsigned short* AO = ws_c + AO_OFF;
  const unsigned short* Wfb = ws_c + WF_OFF;
  int tid = threadIdx.x, w = tid >> 6, lane = tid & 63, g = lane >> 4, r = lane & 15;
  int m0 = blockIdx.x * 16;
  f32x4 acc[4] = {};
  int arow = tid >> 4, acol = (tid & 15) * 4;
  int brow = tid >> 3, bcol = (tid & 7) * 8;
  for (int k0 = 0; k0 < SD; k0 += 64) {
    uint2 av = *reinterpret_cast<const uint2*>(AO + (m0 + arow) * SD + k0 + acol);
    short8 bv[8];
#pragma unroll
    for (int i = 0; i < 8; i++)
      bv[i] = *reinterpret_cast<const short8*>(Wfb + (i * 32 + brow) * SD + k0 + bcol);
    __syncthreads();
    *reinterpret_cast<uint2*>(&Al[arow][acol]) = av;
#pragma unroll
    for (int i = 0; i < 8; i++)
      *reinterpret_cast<short8*>(&Bl[i * 32 + brow][bcol]) = bv[i];
    __syncthreads();
#pragma unroll
    for (int ks = 0; ks < 2; ks++) {
      short8 af = *reinterpret_cast<const short8*>(&Al[r][ks * 32 + g * 8]);
#pragma unroll
      for (int nt = 0; nt < 4; nt++) {
        short8 bb = *reinterpret_cast<const short8*>(&Bl[w * 64 + nt * 16 + r][ks * 32 + g * 8]);
        acc[nt] = __builtin_amdgcn_mfma_f32_16x16x32_bf16(af, bb, acc[nt], 0, 0, 0);
      }
    }
  }
#pragma unroll
  for (int nt = 0; nt < 4; nt++)
#pragma unroll
    for (int j = 0; j < 4; j++)
      Cl[g * 4 + j][w * 64 + nt * 16 + r] = acc[nt][j];
  __syncthreads();
  int row = tid >> 4, sub = tid & 15;
  int m = m0 + row;
  float x[16];
  float sum = 0.f, sumsq = 0.f;
#pragma unroll
  for (int i = 0; i < 4; i++) {
    int col = sub * 16 + i * 4;
    float4 xv = *reinterpret_cast<const float4*>(X + m * SD + col);
    float4 bb = *reinterpret_cast<const float4*>(bfv + col);
    x[i * 4 + 0] = Cl[row][col + 0] + xv.x + bb.x;
    x[i * 4 + 1] = Cl[row][col + 1] + xv.y + bb.y;
    x[i * 4 + 2] = Cl[row][col + 2] + xv.z + bb.z;
    x[i * 4 + 3] = Cl[row][col + 3] + xv.w + bb.w;
  }
#pragma unroll
  for (int c = 0; c < 16; c++) { sum += x[c]; sumsq += x[c] * x[c]; }
  sum += __shfl_xor(sum, 1);  sumsq += __shfl_xor(sumsq, 1);
  sum += __shfl_xor(sum, 2);  sumsq += __shfl_xor(sumsq, 2);
  sum += __shfl_xor(sum, 4);  sumsq += __shfl_xor(sumsq, 4);
  sum += __shfl_xor(sum, 8);  sumsq += __shfl_xor(sumsq, 8);
  float mean = sum * (1.0f / 256.0f);
  float var = sumsq * (1.0f / 256.0f) - mean * mean;
  float rstd = rsqrtf(var + 1e-6f);
#pragma unroll
  for (int i = 0; i < 4; i++) {
    int col = sub * 16 + i * 4;
    float4 gv = *reinterpret_cast<const float4*>(gamma + col);
    float4 bv2 = *reinterpret_cast<const float4*>(beta + col);
    float4 ov;
    ov.x = (x[i * 4 + 0] - mean) * rstd * gv.x + bv2.x;
    ov.y = (x[i * 4 + 1] - mean) * rstd * gv.y + bv2.y;
    ov.z = (x[i * 4 + 2] - mean) * rstd * gv.z + bv2.z;
    ov.w = (x[i * 4 + 3] - mean) * rstd * gv.w + bv2.w;
    *reinterpret_cast<float4*>(out + m * SD + col) = ov;
  }
}

extern "C" void kernel_launch(void* const* d_in, const int* in_sizes, int n_in,
                              void* d_out, int out_size, void* d_ws, size_t ws_size,
                              hipStream_t stream) {
  const float* X  = (const float*)d_in[0];
  const float* Wq = (const float*)d_in[1];
  const float* Wk = (const float*)d_in[2];
  const float* Wv = (const float*)d_in[3];
  const float* Wf = (const float*)d_in[4];
  const float* bf = (const float*)d_in[5];
  const float* gm = (const float*)d_in[6];
  const float* bt = (const float*)d_in[7];
  float* out = (float*)d_out;
  unsigned short* ws = (unsigned short*)d_ws;

  qkv_k<<<dim3(128, 6), 256, 0, stream>>>(X, Wq, Wk, Wv, Wf, ws);
  attn_k<<<dim3(512), 512, 0, stream>>>(ws, ws);
  final_k<<<512, 256, 0, stream>>>(ws, X, bf, gm, bt, out);
}

// Round 14
// 56.395 us; speedup vs baseline: 1.4014x; 1.4014x over previous
//
#include <hip/hip_runtime.h>
#include <hip/hip_bf16.h>

typedef __attribute__((ext_vector_type(8))) short short8;
typedef __attribute__((ext_vector_type(4))) float f32x4;
typedef __attribute__((ext_vector_type(16))) float f32x16;

#define DEVI __device__ __forceinline__

DEVI unsigned short f2bf(float f) {
  union { float f; unsigned int u; } v; v.f = f;
  unsigned int r = v.u + 0x7fffu + ((v.u >> 16) & 1u);
  return (unsigned short)(r >> 16);
}

DEVI unsigned int cvt2(float lo, float hi) {  // v_cvt_pk_bf16_f32 (RNE)
  unsigned int r;
  asm("v_cvt_pk_bf16_f32 %0, %1, %2" : "=v"(r) : "v"(lo), "v"(hi));
  return r;
}

// direct global->LDS, 16B per lane. dest = wave-uniform base + lane*16 (linear).
#define GLDS16(gp, lp)                                                         \
  __builtin_amdgcn_global_load_lds(                                            \
      (const __attribute__((address_space(1))) unsigned int*)(uintptr_t)(gp),  \
      (__attribute__((address_space(3))) unsigned int*)(uintptr_t)(lp), 16, 0, 0)

// problem sizes
#define SB 4
#define SS 2048
#define SD 256
#define SH 8
#define SDH 32
#define SM 8192
#define WN (SD * SD)

#define QSCALE 0.0318793654f

// workspace layout (ushort element offsets)
#define Q_OFF   0                 // [BH][S][dh]   (Q pre-scaled by QSCALE)
#define K_OFF   (SM * SD)         // [BH][S][dh]
#define VT_OFF  (2 * SM * SD)     // [BH][dh][S]
#define AO_OFF  (3 * SM * SD)     // [M][D] attention output
#define XB_OFF  (4 * SM * SD)     // [M][D] X in bf16
#define W_OFF   (5 * SM * SD)     // Wq|Wk|Wv|Wf bf16, contiguous

// ---------------- kernel 0: fp32 -> bf16 conversion (R0-proven body) --------
__global__ __launch_bounds__(256) void convert_k(
    const float* __restrict__ X, const float* __restrict__ Wq,
    const float* __restrict__ Wk, const float* __restrict__ Wv,
    const float* __restrict__ Wf, unsigned short* __restrict__ ws) {
  const int XN = SM * SD;
  int i4 = (blockIdx.x * 256 + threadIdx.x) * 4;
  const float* src; unsigned short* dst; int idx;
  if (i4 < XN)             { src = X;  dst = ws + XB_OFF;       idx = i4; }
  else if (i4 < XN + WN)   { src = Wq; dst = ws + W_OFF;        idx = i4 - XN; }
  else if (i4 < XN + 2*WN) { src = Wk; dst = ws + W_OFF + WN;   idx = i4 - XN - WN; }
  else if (i4 < XN + 3*WN) { src = Wv; dst = ws + W_OFF + 2*WN; idx = i4 - XN - 2*WN; }
  else if (i4 < XN + 4*WN) { src = Wf; dst = ws + W_OFF + 3*WN; idx = i4 - XN - 3*WN; }
  else return;
  float4 v = *reinterpret_cast<const float4*>(src + idx);
  unsigned short o[4] = { f2bf(v.x), f2bf(v.y), f2bf(v.z), f2bf(v.w) };
  *reinterpret_cast<uint2*>(dst + idx) = *reinterpret_cast<const uint2*>(o);
}

// ---------------- kernel 1: QKV projection, 64x128 tile, GLDS16 staging -----
// Grid (128,6) = 768 blocks = 3/CU. All-bf16 inputs from ws. Staging is pure
// global_load_lds (6 issues/wave/K-step, dbuf, counted vmcnt(6)). LDS swizzle
// per rule 21: linear dest + inverse-swizzled global source (chunk^=row&7 on
// 16B chunks) + same involution on frag reads -> all 8 bank-groups balanced.
__global__ __launch_bounds__(256) void qkv_k(const unsigned short* __restrict__ ws_c,
                                             unsigned short* __restrict__ ws) {
  __shared__ __align__(16) unsigned short Ab[2][64 * 64];
  __shared__ __align__(16) unsigned short Bb[2][128 * 64];
  int tid = threadIdx.x, w = tid >> 6, lane = tid & 63, g = lane >> 4, r = lane & 15;
  int m0 = blockIdx.x * 64;
  int z = blockIdx.y >> 1, nbase = (blockIdx.y & 1) * 128;
  const unsigned short* Xb = ws_c + XB_OFF;
  const unsigned short* Wall = ws_c + W_OFF + (z * 256 + nbase) * SD;
  // staging source (inverse-swizzled): lane -> LDS byte lane*16 within issue
  int lr = lane >> 3, lc = lane & 7;
  int cg = lc ^ lr;  // lr in 0..7
  const unsigned short* srcA = Xb + (m0 + w * 16 + lr) * SD + cg * 8;
  const unsigned short* srcB = Wall + (w * 32 + lr) * SD + cg * 8;
  auto stage = [&](int buf, int k0) {
    unsigned short* da = &Ab[buf][w * 1024];
    unsigned short* db = &Bb[buf][w * 2048];
#pragma unroll
    for (int j = 0; j < 2; ++j) GLDS16(srcA + j * 8 * SD + k0, da + j * 512);
#pragma unroll
    for (int j = 0; j < 4; ++j) GLDS16(srcB + j * 8 * SD + k0, db + j * 512);
  };
  stage(0, 0);
  int wr = (w >> 1) * 32, wc = (w & 1) * 64;
  f32x4 acc[2][4] = {};
  // frag-read chunk offsets (ush): chunk' = (ks*4+g) ^ (row&7), row&7 == r&7
  int ks0 = (g ^ (r & 7)) * 8;
  int ks1 = ((4 + g) ^ (r & 7)) * 8;
  for (int step = 0; step < 4; ++step) {
    if (step < 3) {
      stage((step + 1) & 1, (step + 1) * 64);
      asm volatile("s_waitcnt vmcnt(6)" ::: "memory");  // current tile landed
    } else {
      asm volatile("s_waitcnt vmcnt(0)" ::: "memory");
    }
    __builtin_amdgcn_s_barrier();
    const unsigned short* At = &Ab[step & 1][0];
    const unsigned short* Bt = &Bb[step & 1][0];
#pragma unroll
    for (int ks = 0; ks < 2; ++ks) {
      int co = ks ? ks1 : ks0;
      short8 af[2], bf[4];
#pragma unroll
      for (int i = 0; i < 2; ++i)
        af[i] = *reinterpret_cast<const short8*>(At + (wr + i * 16 + r) * 64 + co);
#pragma unroll
      for (int j = 0; j < 4; ++j)
        bf[j] = *reinterpret_cast<const short8*>(Bt + (wc + j * 16 + r) * 64 + co);
#pragma unroll
      for (int i = 0; i < 2; ++i)
#pragma unroll
        for (int j = 0; j < 4; ++j)
          acc[i][j] = __builtin_amdgcn_mfma_f32_16x16x32_bf16(af[i], bf[j], acc[i][j], 0, 0, 0);
    }
    __builtin_amdgcn_s_barrier();
  }
  // epilogue (R10-proven pattern); scratch overlays Ab (16KB)
  int b_ = m0 >> 11, sbase = m0 & 2047;
  float qs = (z == 0) ? QSCALE : 1.0f;
  unsigned short* Ct = &Ab[0][0];  // [64][72] for Q/K, [64][80] for V^T
#pragma unroll
  for (int p = 0; p < 2; ++p) {    // n-half pass: local cols p*64 .. p*64+63
    __syncthreads();
    if ((w & 1) == p) {
      if (z < 2) {
#pragma unroll
        for (int i = 0; i < 2; ++i)
#pragma unroll
          for (int j = 0; j < 4; ++j)
#pragma unroll
            for (int jj = 0; jj < 4; ++jj)
              Ct[(wr + i * 16 + g * 4 + jj) * 72 + j * 16 + r] = f2bf(acc[i][j][jj] * qs);
      } else {
#pragma unroll
        for (int i = 0; i < 2; ++i)
#pragma unroll
          for (int j = 0; j < 4; ++j) {
            unsigned short o4[4];
#pragma unroll
            for (int jj = 0; jj < 4; ++jj) o4[jj] = f2bf(acc[i][j][jj]);
            *reinterpret_cast<uint2*>(&Ct[(j * 16 + r) * 80 + wr + i * 16 + g * 4]) =
                *reinterpret_cast<const uint2*>(o4);
          }
      }
    }
    __syncthreads();
    if (z < 2) {
      unsigned short* out = ws + (z == 0 ? Q_OFF : K_OFF);
      int h0 = (nbase + p * 64) >> 5;
#pragma unroll
      for (int it = 0; it < 2; ++it) {
        int c = it * 256 + tid;                  // 512 chunks of 16B
        int m = c >> 3, cr = c & 7, hl = cr >> 2, ch = cr & 3;
        short8 val = *reinterpret_cast<const short8*>(&Ct[m * 72 + hl * 32 + ch * 8]);
        int h = h0 + hl;
        *reinterpret_cast<short8*>(
            out + (((b_ << 3) + h) * SS + sbase + m) * SDH + ch * 8) = val;
      }
    } else {
      unsigned short* out = ws + VT_OFF;
      int nb = nbase + p * 64;
#pragma unroll
      for (int it = 0; it < 2; ++it) {
        int c = it * 256 + tid;                  // 512 chunks of 16B
        int nl = c >> 3, ch = c & 7;
        short8 val = *reinterpret_cast<const short8*>(&Ct[nl * 80 + ch * 8]);
        int col = nb + nl, h = col >> 5, d = col & 31;
        *reinterpret_cast<short8*>(
            out + ((((b_ << 3) + h) << 5) + d) * SS + sbase + ch * 8) = val;
      }
    }
  }
}

// ---------------- kernel 2: flash attention (R10-proven, single rep) --------
__global__ __launch_bounds__(512, 4) void attn_k(const unsigned short* __restrict__ ws_c,
                                                 unsigned short* __restrict__ ws) {
  __shared__ __align__(16) unsigned char smem[65536];
  int tid = threadIdx.x, w = tid >> 6, lane = tid & 63;
  int wg = w >> 2, wl = w & 3, gtid = tid & 255;
  int n32 = lane & 31, hi = lane >> 5;
  int wgid = ((blockIdx.x & 7) << 6) + (blockIdx.x >> 3);
  int bh = wgid >> 4, qb = wgid & 15;
  int q0 = qb * 128 + wl * 32;
  const unsigned short* Qh = ws_c + Q_OFF + bh * (SS * SDH);
  const unsigned short* Kg = ws_c + K_OFF + (bh * SS + wg * 1024) * SDH;
  const unsigned short* Vg = ws_c + VT_OFF + bh * (SDH * SS) + wg * 1024;
  short8 qB0 = *reinterpret_cast<const short8*>(Qh + (q0 + n32) * SDH + 8 * hi);
  short8 qB1 = *reinterpret_cast<const short8*>(Qh + (q0 + n32) * SDH + 16 + 8 * hi);
  unsigned short* Kbuf0 = (unsigned short*)(smem + wg * 16384);
  unsigned short* Kbuf1 = (unsigned short*)(smem + wg * 16384 + 8192);
  unsigned short* Vbuf0 = (unsigned short*)(smem + 32768 + wg * 16384);
  unsigned short* Vbuf1 = (unsigned short*)(smem + 32768 + wg * 16384 + 8192);
  int wv = gtid >> 6;
  int kr = gtid >> 2;
  int kcg = (gtid & 3) ^ ((kr >> 1) & 3);
  const unsigned short* gK0 = Kg + kr * SDH + kcg * 8;
  const unsigned short* gK1 = gK0 + 64 * SDH;
  int vr = gtid >> 4;
  int vcg = (gtid & 15) ^ (vr & 7);
  const unsigned short* gV0 = Vg + vr * SS + vcg * 8;
  const unsigned short* gV1 = gV0 + 16 * SS;
  auto issue = [&](int buf, int tt) {
    char* kd = (char*)(buf ? Kbuf1 : Kbuf0) + wv * 1024;
    char* vd = (char*)(buf ? Vbuf1 : Vbuf0) + wv * 1024;
    GLDS16(gK0 + tt * 4096, kd);
    GLDS16(gK1 + tt * 4096, kd + 4096);
    GLDS16(gV0 + tt * 128, vd);
    GLDS16(gV1 + tt * 128, vd + 4096);
  };
  issue(0, 0);
  f32x16 O = {}, Lf = {};
  union { unsigned int u[4]; short8 sv; } ONES;
  ONES.u[0] = 0x3F803F80u; ONES.u[1] = 0x3F803F80u;
  ONES.u[2] = 0x3F803F80u; ONES.u[3] = 0x3F803F80u;
  int rb = (n32 >> 1) & 3;
  int koff0 = (hi ^ rb) * 8;
  int koff1 = ((2 + hi) ^ rb) * 8;
  int vb7 = n32 & 7;
  for (int t = 0; t < 8; ++t) {
    const unsigned short* Kt = (t & 1) ? Kbuf1 : Kbuf0;
    const unsigned short* Vt = (t & 1) ? Vbuf1 : Vbuf0;
    if (t < 7) {
      issue((t + 1) & 1, t + 1);
      asm volatile("s_waitcnt vmcnt(4)" ::: "memory");
    } else {
      asm volatile("s_waitcnt vmcnt(0)" ::: "memory");
    }
    __builtin_amdgcn_s_barrier();
#pragma unroll
    for (int si = 0; si < 4; ++si) {
      int s = (si + wl) & 3;
      const unsigned short* krow = Kt + (s * 32 + n32) * 32;
      short8 ka = *reinterpret_cast<const short8*>(krow + koff0);
      short8 kb = *reinterpret_cast<const short8*>(krow + koff1);
      f32x16 aC = {};
      __builtin_amdgcn_s_setprio(1);
      aC = __builtin_amdgcn_mfma_f32_32x32x16_bf16(ka, qB0, aC, 0, 0, 0);
      aC = __builtin_amdgcn_mfma_f32_32x32x16_bf16(kb, qB1, aC, 0, 0, 0);
      __builtin_amdgcn_s_setprio(0);
#pragma unroll
      for (int i = 0; i < 16; ++i) aC[i] = __builtin_amdgcn_exp2f(aC[i]);
      unsigned int pk[8];
#pragma unroll
      for (int i = 0; i < 8; ++i) pk[i] = cvt2(aC[2 * i], aC[2 * i + 1]);
      asm("v_permlane32_swap_b32 %0, %1" : "+v"(pk[0]), "+v"(pk[2]));
      asm("v_permlane32_swap_b32 %0, %1" : "+v"(pk[1]), "+v"(pk[3]));
      asm("v_permlane32_swap_b32 %0, %1" : "+v"(pk[4]), "+v"(pk[6]));
      asm("v_permlane32_swap_b32 %0, %1" : "+v"(pk[5]), "+v"(pk[7]));
      union { unsigned int u[4]; short8 sv; } A1, A2;
      A1.u[0] = pk[0]; A1.u[1] = pk[1]; A1.u[2] = pk[2]; A1.u[3] = pk[3];
      A2.u[0] = pk[4]; A2.u[1] = pk[5]; A2.u[2] = pk[6]; A2.u[3] = pk[7];
      const unsigned short* vrow = Vt + n32 * 128;
      short8 vB0 = *reinterpret_cast<const short8*>(vrow + ((s * 4 + hi) ^ vb7) * 8);
      short8 vB1 = *reinterpret_cast<const short8*>(vrow + ((s * 4 + 2 + hi) ^ vb7) * 8);
      __builtin_amdgcn_s_setprio(1);
      O  = __builtin_amdgcn_mfma_f32_32x32x16_bf16(A1.sv, vB0, O, 0, 0, 0);
      O  = __builtin_amdgcn_mfma_f32_32x32x16_bf16(A2.sv, vB1, O, 0, 0, 0);
      Lf = __builtin_amdgcn_mfma_f32_32x32x16_bf16(A1.sv, ONES.sv, Lf, 0, 0, 0);
      Lf = __builtin_amdgcn_mfma_f32_32x32x16_bf16(A2.sv, ONES.sv, Lf, 0, 0, 0);
      __builtin_amdgcn_s_setprio(0);
    }
    __builtin_amdgcn_s_barrier();
  }
  __syncthreads();
  float* OCf = reinterpret_cast<float*>(smem);           // [16][257]
  float* LCf = OCf + 16 * 257;
  int p = wl * 64 + lane;
  if (wg == 1) {
#pragma unroll
    for (int i = 0; i < 16; ++i) { OCf[i * 257 + p] = O[i]; LCf[i * 257 + p] = Lf[i]; }
  }
  __syncthreads();
  if (wg == 0) {
    int b = bh >> 3, h = bh & 7;
    unsigned short* AO = ws + AO_OFF;
#pragma unroll
    for (int rr = 0; rr < 16; ++rr) {
      float Ot = O[rr] + OCf[rr * 257 + p];
      float Lt = Lf[rr] + LCf[rr * 257 + p];
      int q = (rr & 3) + 8 * (rr >> 2) + 4 * hi;
      AO[(b * SS + q0 + q) * SD + h * SDH + n32] = f2bf(Ot / Lt);
    }
  }
}

// ---------------- kernel 3: out-proj + bias + residual + LayerNorm ----------
// (R10-proven; Wf bf16 now at W_OFF + 3*WN)
__global__ __launch_bounds__(256) void final_k(
    const unsigned short* __restrict__ ws_c, const float* __restrict__ X,
    const float* __restrict__ bfv, const float* __restrict__ gamma,
    const float* __restrict__ beta, float* __restrict__ out) {
  __shared__ __align__(16) unsigned short Al[16][72];
  __shared__ __align__(16) unsigned short Bl[256][72];
  __shared__ float Cl[16][257];
  const unsigned short* AO = ws_c + AO_OFF;
  const unsigned short* Wfb = ws_c + W_OFF + 3 * WN;
  int tid = threadIdx.x, w = tid >> 6, lane = tid & 63, g = lane >> 4, r = lane & 15;
  int m0 = blockIdx.x * 16;
  f32x4 acc[4] = {};
  int arow = tid >> 4, acol = (tid & 15) * 4;
  int brow = tid >> 3, bcol = (tid & 7) * 8;
  for (int k0 = 0; k0 < SD; k0 += 64) {
    uint2 av = *reinterpret_cast<const uint2*>(AO + (m0 + arow) * SD + k0 + acol);
    short8 bv[8];
#pragma unroll
    for (int i = 0; i < 8; i++)
      bv[i] = *reinterpret_cast<const short8*>(Wfb + (i * 32 + brow) * SD + k0 + bcol);
    __syncthreads();
    *reinterpret_cast<uint2*>(&Al[arow][acol]) = av;
#pragma unroll
    for (int i = 0; i < 8; i++)
      *reinterpret_cast<short8*>(&Bl[i * 32 + brow][bcol]) = bv[i];
    __syncthreads();
#pragma unroll
    for (int ks = 0; ks < 2; ks++) {
      short8 af = *reinterpret_cast<const short8*>(&Al[r][ks * 32 + g * 8]);
#pragma unroll
      for (int nt = 0; nt < 4; nt++) {
        short8 bb = *reinterpret_cast<const short8*>(&Bl[w * 64 + nt * 16 + r][ks * 32 + g * 8]);
        acc[nt] = __builtin_amdgcn_mfma_f32_16x16x32_bf16(af, bb, acc[nt], 0, 0, 0);
      }
    }
  }
#pragma unroll
  for (int nt = 0; nt < 4; nt++)
#pragma unroll
    for (int j = 0; j < 4; j++)
      Cl[g * 4 + j][w * 64 + nt * 16 + r] = acc[nt][j];
  __syncthreads();
  int row = tid >> 4, sub = tid & 15;
  int m = m0 + row;
  float x[16];
  float sum = 0.f, sumsq = 0.f;
#pragma unroll
  for (int i = 0; i < 4; i++) {
    int col = sub * 16 + i * 4;
    float4 xv = *reinterpret_cast<const float4*>(X + m * SD + col);
    float4 bb = *reinterpret_cast<const float4*>(bfv + col);
    x[i * 4 + 0] = Cl[row][col + 0] + xv.x + bb.x;
    x[i * 4 + 1] = Cl[row][col + 1] + xv.y + bb.y;
    x[i * 4 + 2] = Cl[row][col + 2] + xv.z + bb.z;
    x[i * 4 + 3] = Cl[row][col + 3] + xv.w + bb.w;
  }
#pragma unroll
  for (int c = 0; c < 16; c++) { sum += x[c]; sumsq += x[c] * x[c]; }
  sum += __shfl_xor(sum, 1);  sumsq += __shfl_xor(sumsq, 1);
  sum += __shfl_xor(sum, 2);  sumsq += __shfl_xor(sumsq, 2);
  sum += __shfl_xor(sum, 4);  sumsq += __shfl_xor(sumsq, 4);
  sum += __shfl_xor(sum, 8);  sumsq += __shfl_xor(sumsq, 8);
  float mean = sum * (1.0f / 256.0f);
  float var = sumsq * (1.0f / 256.0f) - mean * mean;
  float rstd = rsqrtf(var + 1e-6f);
#pragma unroll
  for (int i = 0; i < 4; i++) {
    int col = sub * 16 + i * 4;
    float4 gv = *reinterpret_cast<const float4*>(gamma + col);
    float4 bv2 = *reinterpret_cast<const float4*>(beta + col);
    float4 ov;
    ov.x = (x[i * 4 + 0] - mean) * rstd * gv.x + bv2.x;
    ov.y = (x[i * 4 + 1] - mean) * rstd * gv.y + bv2.y;
    ov.z = (x[i * 4 + 2] - mean) * rstd * gv.z + bv2.z;
    ov.w = (x[i * 4 + 3] - mean) * rstd * gv.w + bv2.w;
    *reinterpret_cast<float4*>(out + m * SD + col) = ov;
  }
}

extern "C" void kernel_launch(void* const* d_in, const int* in_sizes, int n_in,
                              void* d_out, int out_size, void* d_ws, size_t ws_size,
                              hipStream_t stream) {
  const float* X  = (const float*)d_in[0];
  const float* Wq = (const float*)d_in[1];
  const float* Wk = (const float*)d_in[2];
  const float* Wv = (const float*)d_in[3];
  const float* Wf = (const float*)d_in[4];
  const float* bf = (const float*)d_in[5];
  const float* gm = (const float*)d_in[6];
  const float* bt = (const float*)d_in[7];
  float* out = (float*)d_out;
  unsigned short* ws = (unsigned short*)d_ws;

  convert_k<<<2304, 256, 0, stream>>>(X, Wq, Wk, Wv, Wf, ws);
  qkv_k<<<dim3(128, 6), 256, 0, stream>>>(ws, ws);
  attn_k<<<dim3(512), 512, 0, stream>>>(ws, ws);
  final_k<<<512, 256, 0, stream>>>(ws, X, bf, gm, bt, out);
}

// Round 15
// 54.586 us; speedup vs baseline: 1.4479x; 1.0332x over previous
//
#include <hip/hip_runtime.h>
#include <hip/hip_bf16.h>

typedef __attribute__((ext_vector_type(8))) short short8;
typedef __attribute__((ext_vector_type(4))) float f32x4;
typedef __attribute__((ext_vector_type(16))) float f32x16;

#define DEVI __device__ __forceinline__

DEVI unsigned short f2bf(float f) {
  union { float f; unsigned int u; } v; v.f = f;
  unsigned int r = v.u + 0x7fffu + ((v.u >> 16) & 1u);
  return (unsigned short)(r >> 16);
}

DEVI unsigned int cvt2(float lo, float hi) {  // v_cvt_pk_bf16_f32 (RNE)
  unsigned int r;
  asm("v_cvt_pk_bf16_f32 %0, %1, %2" : "=v"(r) : "v"(lo), "v"(hi));
  return r;
}

// direct global->LDS, 16B per lane. dest = wave-uniform base + lane*16 (linear).
#define GLDS16(gp, lp)                                                         \
  __builtin_amdgcn_global_load_lds(                                            \
      (const __attribute__((address_space(1))) unsigned int*)(uintptr_t)(gp),  \
      (__attribute__((address_space(3))) unsigned int*)(uintptr_t)(lp), 16, 0, 0)

// problem sizes
#define SB 4
#define SS 2048
#define SD 256
#define SH 8
#define SDH 32
#define SM 8192

// softmax scale folded into Q:  (1/sqrt(S)) * log2(e)
#define QSCALE 0.0318793654f

// workspace layout (ushort element offsets) -- all bf16 intermediates
#define Q_OFF   0                 // [BH][S][dh]   (Q pre-scaled by QSCALE)
#define K_OFF   (SM * SD)         // [BH][S][dh]
#define VT_OFF  (2 * SM * SD)     // [BH][dh][S]  (V transposed)
#define AO_OFF  (3 * SM * SD)     // [M][D] attention output
#define WF_OFF  (4 * SM * SD)     // [256][256] Wf in bf16 (converted by qkv_k)

// ---------------- kernel 1: fused convert + QKV projection, 64x128 tile -----
// Grid 128x6 = 768 blocks = EXACTLY 3/CU. z = y>>1 selects Wq/Wk/Wv;
// nbase = (y&1)*128. fp32 in-register convert while staging. Epilogue via LDS
// for coalesced stores. z==2 blocks also convert a slice of Wf to bf16.
__global__ __launch_bounds__(256) void qkv_k(
    const float* __restrict__ X, const float* __restrict__ Wq,
    const float* __restrict__ Wk, const float* __restrict__ Wv,
    const float* __restrict__ Wf, unsigned short* __restrict__ ws) {
  __shared__ __align__(16) unsigned short Atile[64][72];
  __shared__ __align__(16) unsigned short Btile[128][72];
  int tid = threadIdx.x, w = tid >> 6, lane = tid & 63, g = lane >> 4, r = lane & 15;
  int m0 = blockIdx.x * 64;
  int z = blockIdx.y >> 1, nbase = (blockIdx.y & 1) * 128;
  const float* Wz = (z == 0) ? Wq : (z == 1) ? Wk : Wv;
  if (z == 2) {  // Wf fp32 -> bf16, 256 floats per block (slice disjoint)
    int slice = blockIdx.x + (nbase ? 128 : 0);
    ws[WF_OFF + slice * 256 + tid] = f2bf(Wf[slice * 256 + tid]);
  }
  int wr = (w >> 1) * 32, wc = (w & 1) * 64;
  f32x4 acc[2][4] = {};
  int srow = tid >> 3, scol = (tid & 7) * 8;
  float4 a0[2], a1[2], b0[4], b1[4];
#pragma unroll
  for (int p = 0; p < 2; ++p) {
    const float* xa = X + (m0 + srow + p * 32) * SD + scol;
    a0[p] = *reinterpret_cast<const float4*>(xa);
    a1[p] = *reinterpret_cast<const float4*>(xa + 4);
  }
#pragma unroll
  for (int p = 0; p < 4; ++p) {
    const float* xb = Wz + (nbase + srow + p * 32) * SD + scol;
    b0[p] = *reinterpret_cast<const float4*>(xb);
    b1[p] = *reinterpret_cast<const float4*>(xb + 4);
  }
  for (int k0 = 0; k0 < SD; k0 += 64) {
    __syncthreads();
#pragma unroll
    for (int p = 0; p < 2; ++p) {
      uint4 ua = { cvt2(a0[p].x, a0[p].y), cvt2(a0[p].z, a0[p].w),
                   cvt2(a1[p].x, a1[p].y), cvt2(a1[p].z, a1[p].w) };
      *reinterpret_cast<uint4*>(&Atile[srow + p * 32][scol]) = ua;
    }
#pragma unroll
    for (int p = 0; p < 4; ++p) {
      uint4 ub = { cvt2(b0[p].x, b0[p].y), cvt2(b0[p].z, b0[p].w),
                   cvt2(b1[p].x, b1[p].y), cvt2(b1[p].z, b1[p].w) };
      *reinterpret_cast<uint4*>(&Btile[srow + p * 32][scol]) = ub;
    }
    __syncthreads();
    if (k0 + 64 < SD) {
#pragma unroll
      for (int p = 0; p < 2; ++p) {
        const float* xa = X + (m0 + srow + p * 32) * SD + k0 + 64 + scol;
        a0[p] = *reinterpret_cast<const float4*>(xa);
        a1[p] = *reinterpret_cast<const float4*>(xa + 4);
      }
#pragma unroll
      for (int p = 0; p < 4; ++p) {
        const float* xb = Wz + (nbase + srow + p * 32) * SD + k0 + 64 + scol;
        b0[p] = *reinterpret_cast<const float4*>(xb);
        b1[p] = *reinterpret_cast<const float4*>(xb + 4);
      }
    }
#pragma unroll
    for (int ks = 0; ks < 2; ++ks) {
      short8 af[2], bf[4];
#pragma unroll
      for (int i = 0; i < 2; ++i)
        af[i] = *reinterpret_cast<const short8*>(&Atile[wr + i * 16 + r][ks * 32 + g * 8]);
#pragma unroll
      for (int j = 0; j < 4; ++j)
        bf[j] = *reinterpret_cast<const short8*>(&Btile[wc + j * 16 + r][ks * 32 + g * 8]);
#pragma unroll
      for (int i = 0; i < 2; ++i)
#pragma unroll
        for (int j = 0; j < 4; ++j)
          acc[i][j] = __builtin_amdgcn_mfma_f32_16x16x32_bf16(af[i], bf[j], acc[i][j], 0, 0, 0);
    }
  }
  int b_ = m0 >> 11, sbase = m0 & 2047;
  float qs = (z == 0) ? QSCALE : 1.0f;
  unsigned short* Vt = &Btile[0][0];  // reused as [64 n][80 m-pad]
#pragma unroll
  for (int p = 0; p < 2; ++p) {       // n-half pass: local cols p*64 .. p*64+63
    __syncthreads();
    if ((w & 1) == p) {
      if (z < 2) {
#pragma unroll
        for (int i = 0; i < 2; ++i)
#pragma unroll
          for (int j = 0; j < 4; ++j)
#pragma unroll
            for (int jj = 0; jj < 4; ++jj)
              Atile[wr + i * 16 + g * 4 + jj][j * 16 + r] = f2bf(acc[i][j][jj] * qs);
      } else {
#pragma unroll
        for (int i = 0; i < 2; ++i)
#pragma unroll
          for (int j = 0; j < 4; ++j) {
            unsigned short o4[4];
#pragma unroll
            for (int jj = 0; jj < 4; ++jj) o4[jj] = f2bf(acc[i][j][jj]);
            *reinterpret_cast<uint2*>(&Vt[(j * 16 + r) * 80 + wr + i * 16 + g * 4]) =
                *reinterpret_cast<const uint2*>(o4);
          }
      }
    }
    __syncthreads();
    if (z < 2) {
      unsigned short* out = ws + (z == 0 ? Q_OFF : K_OFF);
      int h0 = (nbase + p * 64) >> 5;
#pragma unroll
      for (int it = 0; it < 2; ++it) {
        int c = it * 256 + tid;                  // 512 chunks of 16B
        int m = c >> 3, cr = c & 7, hl = cr >> 2, ch = cr & 3;
        short8 val = *reinterpret_cast<const short8*>(&Atile[m][hl * 32 + ch * 8]);
        int h = h0 + hl;
        *reinterpret_cast<short8*>(
            out + (((b_ << 3) + h) * SS + sbase + m) * SDH + ch * 8) = val;
      }
    } else {
      unsigned short* out = ws + VT_OFF;
      int nb = nbase + p * 64;
#pragma unroll
      for (int it = 0; it < 2; ++it) {
        int c = it * 256 + tid;                  // 512 chunks of 16B
        int nl = c >> 3, ch = c & 7;
        short8 val = *reinterpret_cast<const short8*>(&Vt[nl * 80 + ch * 8]);
        int col = nb + nl, h = col >> 5, d = col & 31;
        *reinterpret_cast<short8*>(
            out + ((((b_ << 3) + h) << 5) + d) * SS + sbase + ch * 8) = val;
      }
    }
  }
}

// ---------------- kernel 2: flash attention (proven 54.9us config) ----------
// 512 blocks (32 bh x 16 qb, XCD-swizzled) x 512 thr = 8 waves.
// Waves 0-3: kv [0,1024), waves 4-7: kv [1024,2048); each wave 32 q rows.
// TKV=128, dbuf global_load_lds, counted vmcnt(4), bank-exact XOR swizzles,
// fixed-M softmax (scale*log2e folded into Q), L via ones-MFMA, per-wave
// staggered subtile order.
__global__ __launch_bounds__(512, 4) void attn_k(const unsigned short* __restrict__ ws_c,
                                                 unsigned short* __restrict__ ws) {
  __shared__ __align__(16) unsigned char smem[65536];
  int tid = threadIdx.x, w = tid >> 6, lane = tid & 63;
  int wg = w >> 2, wl = w & 3, gtid = tid & 255;
  int n32 = lane & 31, hi = lane >> 5;
  int wgid = ((blockIdx.x & 7) << 6) + (blockIdx.x >> 3);
  int bh = wgid >> 4, qb = wgid & 15;
  int q0 = qb * 128 + wl * 32;
  const unsigned short* Qh = ws_c + Q_OFF + bh * (SS * SDH);
  const unsigned short* Kg = ws_c + K_OFF + (bh * SS + wg * 1024) * SDH;
  const unsigned short* Vg = ws_c + VT_OFF + bh * (SDH * SS) + wg * 1024;
  short8 qB0 = *reinterpret_cast<const short8*>(Qh + (q0 + n32) * SDH + 8 * hi);
  short8 qB1 = *reinterpret_cast<const short8*>(Qh + (q0 + n32) * SDH + 16 + 8 * hi);
  unsigned short* Kbuf0 = (unsigned short*)(smem + wg * 16384);
  unsigned short* Kbuf1 = (unsigned short*)(smem + wg * 16384 + 8192);
  unsigned short* Vbuf0 = (unsigned short*)(smem + 32768 + wg * 16384);
  unsigned short* Vbuf1 = (unsigned short*)(smem + 32768 + wg * 16384 + 8192);
  int wv = gtid >> 6;
  int kr = gtid >> 2;
  int kcg = (gtid & 3) ^ ((kr >> 1) & 3);
  const unsigned short* gK0 = Kg + kr * SDH + kcg * 8;
  const unsigned short* gK1 = gK0 + 64 * SDH;
  int vr = gtid >> 4;
  int vcg = (gtid & 15) ^ (vr & 7);
  const unsigned short* gV0 = Vg + vr * SS + vcg * 8;
  const unsigned short* gV1 = gV0 + 16 * SS;
  auto issue = [&](int buf, int tt) {
    char* kd = (char*)(buf ? Kbuf1 : Kbuf0) + wv * 1024;
    char* vd = (char*)(buf ? Vbuf1 : Vbuf0) + wv * 1024;
    GLDS16(gK0 + tt * 4096, kd);
    GLDS16(gK1 + tt * 4096, kd + 4096);
    GLDS16(gV0 + tt * 128, vd);
    GLDS16(gV1 + tt * 128, vd + 4096);
  };
  issue(0, 0);
  f32x16 O = {}, Lf = {};
  union { unsigned int u[4]; short8 sv; } ONES;
  ONES.u[0] = 0x3F803F80u; ONES.u[1] = 0x3F803F80u;
  ONES.u[2] = 0x3F803F80u; ONES.u[3] = 0x3F803F80u;
  int rb = (n32 >> 1) & 3;
  int koff0 = (hi ^ rb) * 8;
  int koff1 = ((2 + hi) ^ rb) * 8;
  int vb7 = n32 & 7;
  for (int t = 0; t < 8; ++t) {
    const unsigned short* Kt = (t & 1) ? Kbuf1 : Kbuf0;
    const unsigned short* Vt = (t & 1) ? Vbuf1 : Vbuf0;
    if (t < 7) {
      issue((t + 1) & 1, t + 1);
      asm volatile("s_waitcnt vmcnt(4)" ::: "memory");
    } else {
      asm volatile("s_waitcnt vmcnt(0)" ::: "memory");
    }
    __builtin_amdgcn_s_barrier();
#pragma unroll
    for (int si = 0; si < 4; ++si) {
      int s = (si + wl) & 3;
      const unsigned short* krow = Kt + (s * 32 + n32) * 32;
      short8 ka = *reinterpret_cast<const short8*>(krow + koff0);
      short8 kb = *reinterpret_cast<const short8*>(krow + koff1);
      f32x16 aC = {};
      __builtin_amdgcn_s_setprio(1);
      aC = __builtin_amdgcn_mfma_f32_32x32x16_bf16(ka, qB0, aC, 0, 0, 0);
      aC = __builtin_amdgcn_mfma_f32_32x32x16_bf16(kb, qB1, aC, 0, 0, 0);
      __builtin_amdgcn_s_setprio(0);
#pragma unroll
      for (int i = 0; i < 16; ++i) aC[i] = __builtin_amdgcn_exp2f(aC[i]);
      unsigned int pk[8];
#pragma unroll
      for (int i = 0; i < 8; ++i) pk[i] = cvt2(aC[2 * i], aC[2 * i + 1]);
      asm("v_permlane32_swap_b32 %0, %1" : "+v"(pk[0]), "+v"(pk[2]));
      asm("v_permlane32_swap_b32 %0, %1" : "+v"(pk[1]), "+v"(pk[3]));
      asm("v_permlane32_swap_b32 %0, %1" : "+v"(pk[4]), "+v"(pk[6]));
      asm("v_permlane32_swap_b32 %0, %1" : "+v"(pk[5]), "+v"(pk[7]));
      union { unsigned int u[4]; short8 sv; } A1, A2;
      A1.u[0] = pk[0]; A1.u[1] = pk[1]; A1.u[2] = pk[2]; A1.u[3] = pk[3];
      A2.u[0] = pk[4]; A2.u[1] = pk[5]; A2.u[2] = pk[6]; A2.u[3] = pk[7];
      const unsigned short* vrow = Vt + n32 * 128;
      short8 vB0 = *reinterpret_cast<const short8*>(vrow + ((s * 4 + hi) ^ vb7) * 8);
      short8 vB1 = *reinterpret_cast<const short8*>(vrow + ((s * 4 + 2 + hi) ^ vb7) * 8);
      __builtin_amdgcn_s_setprio(1);
      O  = __builtin_amdgcn_mfma_f32_32x32x16_bf16(A1.sv, vB0, O, 0, 0, 0);
      O  = __builtin_amdgcn_mfma_f32_32x32x16_bf16(A2.sv, vB1, O, 0, 0, 0);
      Lf = __builtin_amdgcn_mfma_f32_32x32x16_bf16(A1.sv, ONES.sv, Lf, 0, 0, 0);
      Lf = __builtin_amdgcn_mfma_f32_32x32x16_bf16(A2.sv, ONES.sv, Lf, 0, 0, 0);
      __builtin_amdgcn_s_setprio(0);
    }
    __builtin_amdgcn_s_barrier();
  }
  __syncthreads();
  float* OCf = reinterpret_cast<float*>(smem);           // [16][257]
  float* LCf = OCf + 16 * 257;
  int p = wl * 64 + lane;
  if (wg == 1) {
#pragma unroll
    for (int i = 0; i < 16; ++i) { OCf[i * 257 + p] = O[i]; LCf[i * 257 + p] = Lf[i]; }
  }
  __syncthreads();
  if (wg == 0) {
    int b = bh >> 3, h = bh & 7;
    unsigned short* AO = ws + AO_OFF;
#pragma unroll
    for (int rr = 0; rr < 16; ++rr) {
      float Ot = O[rr] + OCf[rr * 257 + p];
      float Lt = Lf[rr] + LCf[rr * 257 + p];
      int q = (rr & 3) + 8 * (rr >> 2) + 4 * hi;
      AO[(b * SS + q0 + q) * SD + h * SDH + n32] = f2bf(Ot / Lt);
    }
  }
}

// ---------------- kernel 3: out-proj + bias + residual + LayerNorm ----------
// 16-row blocks: grid 512 = 2/CU, 8 waves/CU. Wf bf16 from workspace.
__global__ __launch_bounds__(256) void final_k(
    const unsigned short* __restrict__ ws_c, const float* __restrict__ X,
    const float* __restrict__ bfv, const float* __restrict__ gamma,
    const float* __restrict__ beta, float* __restrict__ out) {
  __shared__ __align__(16) unsigned short Al[16][72];
  __shared__ __align__(16) unsigned short Bl[256][72];
  __shared__ float Cl[16][257];
  const unsigned short* AO = ws_c + AO_OFF;
  const unsigned short* Wfb = ws_c + WF_OFF;
  int tid = threadIdx.x, w = tid >> 6, lane = tid & 63, g = lane >> 4, r = lane & 15;
  int m0 = blockIdx.x * 16;
  f32x4 acc[4] = {};
  int arow = tid >> 4, acol = (tid & 15) * 4;
  int brow = tid >> 3, bcol = (tid & 7) * 8;
  for (int k0 = 0; k0 < SD; k0 += 64) {
    uint2 av = *reinterpret_cast<const uint2*>(AO + (m0 + arow) * SD + k0 + acol);
    short8 bv[8];
#pragma unroll
    for (int i = 0; i < 8; i++)
      bv[i] = *reinterpret_cast<const short8*>(Wfb + (i * 32 + brow) * SD + k0 + bcol);
    __syncthreads();
    *reinterpret_cast<uint2*>(&Al[arow][acol]) = av;
#pragma unroll
    for (int i = 0; i < 8; i++)
      *reinterpret_cast<short8*>(&Bl[i * 32 + brow][bcol]) = bv[i];
    __syncthreads();
#pragma unroll
    for (int ks = 0; ks < 2; ks++) {
      short8 af = *reinterpret_cast<const short8*>(&Al[r][ks * 32 + g * 8]);
#pragma unroll
      for (int nt = 0; nt < 4; nt++) {
        short8 bb = *reinterpret_cast<const short8*>(&Bl[w * 64 + nt * 16 + r][ks * 32 + g * 8]);
        acc[nt] = __builtin_amdgcn_mfma_f32_16x16x32_bf16(af, bb, acc[nt], 0, 0, 0);
      }
    }
  }
#pragma unroll
  for (int nt = 0; nt < 4; nt++)
#pragma unroll
    for (int j = 0; j < 4; j++)
      Cl[g * 4 + j][w * 64 + nt * 16 + r] = acc[nt][j];
  __syncthreads();
  int row = tid >> 4, sub = tid & 15;
  int m = m0 + row;
  float x[16];
  float sum = 0.f, sumsq = 0.f;
#pragma unroll
  for (int i = 0; i < 4; i++) {
    int col = sub * 16 + i * 4;
    float4 xv = *reinterpret_cast<const float4*>(X + m * SD + col);
    float4 bb = *reinterpret_cast<const float4*>(bfv + col);
    x[i * 4 + 0] = Cl[row][col + 0] + xv.x + bb.x;
    x[i * 4 + 1] = Cl[row][col + 1] + xv.y + bb.y;
    x[i * 4 + 2] = Cl[row][col + 2] + xv.z + bb.z;
    x[i * 4 + 3] = Cl[row][col + 3] + xv.w + bb.w;
  }
#pragma unroll
  for (int c = 0; c < 16; c++) { sum += x[c]; sumsq += x[c] * x[c]; }
  sum += __shfl_xor(sum, 1);  sumsq += __shfl_xor(sumsq, 1);
  sum += __shfl_xor(sum, 2);  sumsq += __shfl_xor(sumsq, 2);
  sum += __shfl_xor(sum, 4);  sumsq += __shfl_xor(sumsq, 4);
  sum += __shfl_xor(sum, 8);  sumsq += __shfl_xor(sumsq, 8);
  float mean = sum * (1.0f / 256.0f);
  float var = sumsq * (1.0f / 256.0f) - mean * mean;
  float rstd = rsqrtf(var + 1e-6f);
#pragma unroll
  for (int i = 0; i < 4; i++) {
    int col = sub * 16 + i * 4;
    float4 gv = *reinterpret_cast<const float4*>(gamma + col);
    float4 bv2 = *reinterpret_cast<const float4*>(beta + col);
    float4 ov;
    ov.x = (x[i * 4 + 0] - mean) * rstd * gv.x + bv2.x;
    ov.y = (x[i * 4 + 1] - mean) * rstd * gv.y + bv2.y;
    ov.z = (x[i * 4 + 2] - mean) * rstd * gv.z + bv2.z;
    ov.w = (x[i * 4 + 3] - mean) * rstd * gv.w + bv2.w;
    *reinterpret_cast<float4*>(out + m * SD + col) = ov;
  }
}

extern "C" void kernel_launch(void* const* d_in, const int* in_sizes, int n_in,
                              void* d_out, int out_size, void* d_ws, size_t ws_size,
                              hipStream_t stream) {
  const float* X  = (const float*)d_in[0];
  const float* Wq = (const float*)d_in[1];
  const float* Wk = (const float*)d_in[2];
  const float* Wv = (const float*)d_in[3];
  const float* Wf = (const float*)d_in[4];
  const float* bf = (const float*)d_in[5];
  const float* gm = (const float*)d_in[6];
  const float* bt = (const float*)d_in[7];
  float* out = (float*)d_out;
  unsigned short* ws = (unsigned short*)d_ws;

  qkv_k<<<dim3(128, 6), 256, 0, stream>>>(X, Wq, Wk, Wv, Wf, ws);
  attn_k<<<dim3(512), 512, 0, stream>>>(ws, ws);
  final_k<<<512, 256, 0, stream>>>(ws, X, bf, gm, bt, out);
}